// Round 14
// baseline (155.321 us; speedup 1.0000x reference)
//
#include <hip/hip_runtime.h>
#include <hip/hip_bf16.h>
#include <float.h>

#define B_ 4
#define NH_ 32
#define NKV_ 8
#define D_ 128
#define S_ 16384
#define L_ 16385
#define LP_ 16388   // padded score-row stride (16B-aligned rows)
#define H_ 4096
#define INIT_ 128
#define LOCAL_ 128
#define HEAVY_ 2048
#define CHUNK_ 256
#define NCHUNK_ 65   // 64*256 = 16384, chunk 64 holds only l = 16384

typedef float vf4 __attribute__((ext_vector_type(4)));

__device__ __forceinline__ unsigned f2key(float f) {
  unsigned u = __float_as_uint(f);
  return (u & 0x80000000u) ? ~u : (u | 0x80000000u);
}
__device__ __forceinline__ float key2f(unsigned k) {
  unsigned u = (k & 0x80000000u) ? (k & 0x7FFFFFFFu) : ~k;
  return __uint_as_float(u);
}

__device__ __forceinline__ float4 ntload4(const float* p) {
  vf4 v = __builtin_nontemporal_load((const vf4*)p);
  return make_float4(v.x, v.y, v.z, v.w);
}

// packed min/max reduce over 32 lanes (6 shfl instead of 10).
__device__ __forceinline__ void minmax32(int par, float mn0, float mx0, float& mn, float& mx) {
  float v = par ? -mx0 : mn0;
  float x = par ? mn0 : -mx0;
  v = fminf(v, __shfl_xor(x, 1));
  v = fminf(v, __shfl_xor(v, 2));
  v = fminf(v, __shfl_xor(v, 4));
  v = fminf(v, __shfl_xor(v, 8));
  v = fminf(v, __shfl_xor(v, 16));
  float t = __shfl_xor(v, 1);
  mn = par ? t : v;
  mx = -(par ? v : t);
}

// quantize K row fragment + 4 GQA dots + pair-merged reduce + store (lanes sub<4)
__device__ __forceinline__ void quant_dot_store(float4 kx,
    const float4& q0, const float4& q1, const float4& q2, const float4& q3,
    int sub, int par, float* __restrict__ srowbase, int l) {
  float mn0 = fminf(fminf(kx.x, kx.y), fminf(kx.z, kx.w));
  float mx0 = fmaxf(fmaxf(kx.x, kx.y), fmaxf(kx.z, kx.w));
  float mn, mx;
  minmax32(par, mn0, mx0, mn, mx);
  float rng = mx - mn; rng = (rng == 0.0f) ? 1.0f : rng;
  float scale = 15.0f / rng;          // IEEE divide: match reference rint boundaries
  float s2 = rng * (1.0f / 15.0f);
  float dx = fmaf(fminf(fmaxf(rintf((kx.x - mn) * scale), 0.0f), 15.0f), s2, mn);
  float dy = fmaf(fminf(fmaxf(rintf((kx.y - mn) * scale), 0.0f), 15.0f), s2, mn);
  float dz = fmaf(fminf(fmaxf(rintf((kx.z - mn) * scale), 0.0f), 15.0f), s2, mn);
  float dw = fmaf(fminf(fmaxf(rintf((kx.w - mn) * scale), 0.0f), 15.0f), s2, mn);
  float d0 = dx * q0.x + dy * q0.y + dz * q0.z + dw * q0.w;
  float d1 = dx * q1.x + dy * q1.y + dz * q1.z + dw * q1.w;
  float d2 = dx * q2.x + dy * q2.y + dz * q2.z + dw * q2.w;
  float d3 = dx * q3.x + dy * q3.y + dz * q3.z + dw * q3.w;
  // pair-merged 4-dot butterfly: 6 shfl
  float pa = par ? d1 : d0, xa = par ? d0 : d1;
  pa += __shfl_xor(xa, 1);
  float pb = par ? d3 : d2, xb = par ? d2 : d3;
  pb += __shfl_xor(xb, 1);
  float c = (sub & 2) ? pb : pa, xc = (sub & 2) ? pa : pb;
  c += __shfl_xor(xc, 2);
  c += __shfl_xor(c, 4);
  c += __shfl_xor(c, 8);
  c += __shfl_xor(c, 16);
  if (sub < 4) srowbase[(size_t)sub * LP_ + l] = c * 0.08838834764831845f;
}

// ---------------- Kernel A: q/k/v projections (one wave per output row, 4 batches) ----
__global__ __launch_bounds__(256) void k_proj(const float* __restrict__ hs,
    const float* __restrict__ Wq, const float* __restrict__ Wk, const float* __restrict__ Wv,
    float* __restrict__ qraw, float* __restrict__ kraw, float* __restrict__ vnew) {
  int gw = (blockIdx.x * 256 + threadIdx.x) >> 6;   // 0..6143
  int lane = threadIdx.x & 63;
  const float* W;
  if (gw < 4096)      W = Wq + (size_t)gw * H_;
  else if (gw < 5120) W = Wk + (size_t)(gw - 4096) * H_;
  else                W = Wv + (size_t)(gw - 5120) * H_;
  float a0 = 0.f, a1 = 0.f, a2 = 0.f, a3 = 0.f;
  #pragma unroll 4
  for (int it = 0; it < 16; ++it) {
    int h = it * 256 + lane * 4;
    float4 w4 = ntload4(W + h);   // stream-once: keep out of L2/L3
    float4 x0 = *(const float4*)(hs + 0 * H_ + h);
    float4 x1 = *(const float4*)(hs + 1 * H_ + h);
    float4 x2 = *(const float4*)(hs + 2 * H_ + h);
    float4 x3 = *(const float4*)(hs + 3 * H_ + h);
    a0 += w4.x * x0.x + w4.y * x0.y + w4.z * x0.z + w4.w * x0.w;
    a1 += w4.x * x1.x + w4.y * x1.y + w4.z * x1.z + w4.w * x1.w;
    a2 += w4.x * x2.x + w4.y * x2.y + w4.z * x2.z + w4.w * x2.w;
    a3 += w4.x * x3.x + w4.y * x3.y + w4.z * x3.z + w4.w * x3.w;
  }
  float pa = (lane & 1) ? a1 : a0, xa = (lane & 1) ? a0 : a1;
  pa += __shfl_xor(xa, 1);
  float pb = (lane & 1) ? a3 : a2, xb = (lane & 1) ? a2 : a3;
  pb += __shfl_xor(xb, 1);
  float c = (lane & 2) ? pb : pa, xc = (lane & 2) ? pa : pb;
  c += __shfl_xor(xc, 2);
  c += __shfl_xor(c, 4);
  c += __shfl_xor(c, 8);
  c += __shfl_xor(c, 16);
  c += __shfl_xor(c, 32);
  if (lane < 4) {   // lane r holds sum of batch r
    if (gw < 4096)      qraw[(size_t)lane * H_ + gw] = c;
    else if (gw < 5120) kraw[(size_t)lane * 1024 + (gw - 4096)] = c;
    else                vnew[(size_t)lane * 1024 + (gw - 5120)] = c;
  }
}

// ---------------- Kernel C: fused RoPE + scores with 4-bit pseudo-quantized K ---------
// grid (128, 32): 128 K rows per block; 8-deep load batching for MLP.
__global__ __launch_bounds__(256) void k_scores(const float* __restrict__ kcache,
    const float* __restrict__ kraw, const float* __restrict__ qraw,
    const float* __restrict__ cosv, const float* __restrict__ sinv,
    float* __restrict__ scores) {
  int wave = threadIdx.x >> 6, lane = threadIdx.x & 63;
  int half = lane >> 5, sub = lane & 31;
  int par = sub & 1;
  int bkv = blockIdx.y; int b = bkv >> 3, kv = bkv & 7;
  __shared__ __align__(16) float qsh[512];
  const float* qbase = qraw + (size_t)b * H_ + kv * 512;
  for (int i = threadIdx.x; i < 512; i += 256) {
    int d = i & 127;
    int j = (i & ~127) | ((d + 64) & 127);
    float x = qbase[i];
    float y = qbase[j];
    float p = (d < 64) ? -y : y;
    qsh[i] = x * cosv[d] + p * sinv[d];
  }
  __syncthreads();
  float4 q0 = *(const float4*)(qsh + 0 * 128 + sub * 4);
  float4 q1 = *(const float4*)(qsh + 1 * 128 + sub * 4);
  float4 q2 = *(const float4*)(qsh + 2 * 128 + sub * 4);
  float4 q3 = *(const float4*)(qsh + 3 * 128 + sub * 4);
  const float* kbase = kcache + ((size_t)(b * NKV_ + kv) * S_) * D_;
  float* srowbase = scores + (size_t)(b * NH_ + kv * 4) * LP_;

  int base = blockIdx.x * 128 + wave * 2 + half;
  for (int it8 = 0; it8 < 2; ++it8) {
    float4 kxs[8];
    #pragma unroll
    for (int u = 0; u < 8; ++u) {
      int l = base + (it8 * 8 + u) * 8;
      kxs[u] = ntload4(kbase + (size_t)l * D_ + sub * 4);   // stream-once K
    }
    #pragma unroll
    for (int u = 0; u < 8; ++u) {
      int l = base + (it8 * 8 + u) * 8;
      quant_dot_store(kxs[u], q0, q1, q2, q3, sub, par, srowbase, l);
    }
  }
  // tail: new RoPE'd k row at l = 16384, handled by block 127 half-wave 0
  if (blockIdx.x == 127 && wave == 0 && half == 0) {
    const float* kb = kraw + (size_t)b * 1024 + kv * 128;
    float el[4];
    #pragma unroll
    for (int e = 0; e < 4; ++e) {
      int d = sub * 4 + e;
      float x = kb[d];
      float y = kb[(d + 64) & 127];
      float p = (d < 64) ? -y : y;
      el[e] = x * cosv[d] + p * sinv[d];
    }
    float4 kx = make_float4(el[0], el[1], el[2], el[3]);
    quant_dot_store(kx, q0, q1, q2, q3, sub, par, srowbase, S_);
  }
}

// ---------------- Kernel D: exact 2048th-largest, register-resident radix select ------
// 1024 threads; 16 keys/thread (contiguous float4 loads). Wave-parallel suffix scans.
__global__ __launch_bounds__(1024) void k_topk(const float* __restrict__ scores,
    float* __restrict__ kthM) {
  int row = blockIdx.x;                 // b*32+h
  const float* srow = scores + (size_t)row * LP_;
  __shared__ unsigned binsP[4][4096];   // pass-1 privatized; binsP[0] reused later
  __shared__ unsigned chs[256];
  __shared__ float wmax[16];
  __shared__ unsigned s_cc, s_rem, s_d, s_k;
  int tid = threadIdx.x;
  int wid = tid >> 6, lane = tid & 63;
  unsigned* mybins = binsP[wid >> 2];

  // ---- load 16 contiguous values (4x float4); fold row max (incl. l=16384) ----
  unsigned keys[16];
  float lm = srow[16384];               // always-region: in max, never in histograms
  const float4* s4 = (const float4*)(srow + tid * 16);
  #pragma unroll
  for (int q = 0; q < 4; ++q) {
    float4 v = s4[q];
    lm = fmaxf(lm, fmaxf(fmaxf(v.x, v.y), fmaxf(v.z, v.w)));
    keys[q * 4 + 0] = f2key(v.x);
    keys[q * 4 + 1] = f2key(v.y);
    keys[q * 4 + 2] = f2key(v.z);
    keys[q * 4 + 3] = f2key(v.w);
  }
  #pragma unroll
  for (int m = 1; m < 64; m <<= 1) lm = fmaxf(lm, __shfl_xor(lm, m));
  if (lane == 0) wmax[wid] = lm;

  // ---- pass 1: top 12 bits, 4-way privatized ----
  for (int i = tid; i < 16384; i += 1024) ((unsigned*)binsP)[i] = 0;
  __syncthreads();
  #pragma unroll
  for (int j = 0; j < 16; ++j) {
    int l = tid * 16 + j;
    if (l >= 128 && l < 16257) atomicAdd(&mybins[keys[j] >> 20], 1u);
  }
  __syncthreads();
  if (tid < 256) {
    unsigned c = 0;
    #pragma unroll
    for (int j = 0; j < 16; ++j) {
      int bin = tid * 16 + j;
      c += binsP[0][bin] + binsP[1][bin] + binsP[2][bin] + binsP[3][bin];
    }
    chs[tid] = c;
  }
  __syncthreads();
  // coarse select over chs[256]: 4 bins/lane, wave-parallel suffix scan
  if (wid == 0) {
    unsigned c0 = chs[lane * 4], c1 = chs[lane * 4 + 1];
    unsigned c2 = chs[lane * 4 + 2], c3 = chs[lane * 4 + 3];
    unsigned s4v = c0 + c1 + c2 + c3;
    unsigned suf = s4v;
    #pragma unroll
    for (int off = 1; off < 64; off <<= 1) {
      unsigned t = __shfl_down(suf, off);
      suf += (lane + off < 64) ? t : 0u;
    }
    unsigned sufEx = suf - s4v;
    unsigned S3 = sufEx + c3, S2 = S3 + c2, S1 = S2 + c1, S0 = suf;
    unsigned K = HEAVY_;
    if (S0 >= K && S1 < K) { s_cc = lane * 4 + 0; s_rem = K - S1; }
    if (S1 >= K && S2 < K) { s_cc = lane * 4 + 1; s_rem = K - S2; }
    if (S2 >= K && S3 < K) { s_cc = lane * 4 + 2; s_rem = K - S3; }
    if (S3 >= K && sufEx < K) { s_cc = lane * 4 + 3; s_rem = K - sufEx; }
  }
  __syncthreads();
  // fine select (16 bins within coarse), 4-copy sums
  if (wid == 0 && lane < 16) {
    unsigned cc = s_cc, remc = s_rem;
    int bin = cc * 16 + lane;
    unsigned bv = binsP[0][bin] + binsP[1][bin] + binsP[2][bin] + binsP[3][bin];
    unsigned suf = bv;
    #pragma unroll
    for (int off = 1; off < 16; off <<= 1) {
      unsigned t = __shfl_down(suf, off);
      suf += (lane + off < 16) ? t : 0u;
    }
    unsigned sufEx = suf - bv;
    if (suf >= remc && sufEx < remc) { s_d = (unsigned)bin; s_k = remc - sufEx; }
  }
  __syncthreads();
  unsigned d1 = s_d, K2 = s_k;
  __syncthreads();

  // ---- pass 2: bits 19:8 within d1 ----
  for (int i = tid; i < 4096; i += 1024) binsP[0][i] = 0;
  __syncthreads();
  #pragma unroll
  for (int j = 0; j < 16; ++j) {
    int l = tid * 16 + j;
    if (l >= 128 && l < 16257) {
      unsigned u = keys[j];
      if ((u >> 20) == d1) atomicAdd(&binsP[0][(u >> 8) & 0xFFFu], 1u);
    }
  }
  __syncthreads();
  if (tid < 256) {
    unsigned c = 0;
    #pragma unroll
    for (int j = 0; j < 16; ++j) c += binsP[0][tid * 16 + j];
    chs[tid] = c;
  }
  __syncthreads();
  if (wid == 0) {
    unsigned c0 = chs[lane * 4], c1 = chs[lane * 4 + 1];
    unsigned c2 = chs[lane * 4 + 2], c3 = chs[lane * 4 + 3];
    unsigned s4v = c0 + c1 + c2 + c3;
    unsigned suf = s4v;
    #pragma unroll
    for (int off = 1; off < 64; off <<= 1) {
      unsigned t = __shfl_down(suf, off);
      suf += (lane + off < 64) ? t : 0u;
    }
    unsigned sufEx = suf - s4v;
    unsigned S3 = sufEx + c3, S2 = S3 + c2, S1 = S2 + c1, S0 = suf;
    unsigned K = K2;
    if (S0 >= K && S1 < K) { s_cc = lane * 4 + 0; s_rem = K - S1; }
    if (S1 >= K && S2 < K) { s_cc = lane * 4 + 1; s_rem = K - S2; }
    if (S2 >= K && S3 < K) { s_cc = lane * 4 + 2; s_rem = K - S3; }
    if (S3 >= K && sufEx < K) { s_cc = lane * 4 + 3; s_rem = K - sufEx; }
  }
  __syncthreads();
  if (wid == 0 && lane < 16) {
    unsigned cc = s_cc, remc = s_rem;
    int bin = cc * 16 + lane;
    unsigned bv = binsP[0][bin];
    unsigned suf = bv;
    #pragma unroll
    for (int off = 1; off < 16; off <<= 1) {
      unsigned t = __shfl_down(suf, off);
      suf += (lane + off < 16) ? t : 0u;
    }
    unsigned sufEx = suf - bv;
    if (suf >= remc && sufEx < remc) { s_d = (unsigned)bin; s_k = remc - sufEx; }
  }
  __syncthreads();
  unsigned d2 = s_d, K3 = s_k;
  __syncthreads();

  // ---- pass 3: low 8 bits within (d1,d2) ----
  if (tid < 256) binsP[0][tid] = 0;
  __syncthreads();
  unsigned pref = (d1 << 12) | d2;
  #pragma unroll
  for (int j = 0; j < 16; ++j) {
    int l = tid * 16 + j;
    if (l >= 128 && l < 16257) {
      unsigned u = keys[j];
      if ((u >> 8) == pref) atomicAdd(&binsP[0][u & 0xFFu], 1u);
    }
  }
  __syncthreads();
  if (wid == 0) {
    unsigned c0 = binsP[0][lane * 4], c1 = binsP[0][lane * 4 + 1];
    unsigned c2 = binsP[0][lane * 4 + 2], c3 = binsP[0][lane * 4 + 3];
    unsigned s4v = c0 + c1 + c2 + c3;
    unsigned suf = s4v;
    #pragma unroll
    for (int off = 1; off < 64; off <<= 1) {
      unsigned t = __shfl_down(suf, off);
      suf += (lane + off < 64) ? t : 0u;
    }
    unsigned sufEx = suf - s4v;
    unsigned S3 = sufEx + c3, S2 = S3 + c2, S1 = S2 + c1, S0 = suf;
    unsigned K = K3;
    int bb = -1;
    if (S0 >= K && S1 < K) bb = lane * 4 + 0;
    if (S1 >= K && S2 < K) bb = lane * 4 + 1;
    if (S2 >= K && S3 < K) bb = lane * 4 + 2;
    if (S3 >= K && sufEx < K) bb = lane * 4 + 3;
    if (bb >= 0) {
      unsigned ku = (d1 << 20) | (d2 << 8) | (unsigned)bb;
      float m = wmax[0];
      #pragma unroll
      for (int k = 1; k < 16; ++k) m = fmaxf(m, wmax[k]);
      kthM[row * 2 + 0] = key2f(ku);
      kthM[row * 2 + 1] = m;
    }
  }
}

// ---------------- Kernel E: union keep-list over 4 GQA heads + shared V gather --------
// grid (NCHUNK_, 32). Slim LDS (~13KB); nontemporal V gather (single-use stream).
__global__ __launch_bounds__(256) void k_pv(const float* __restrict__ scores,
    const float* __restrict__ kthM, const float* __restrict__ vcache,
    const float* __restrict__ vnew, float* __restrict__ partials) {
  int chunk = blockIdx.x, bkv = blockIdx.y;
  int b = bkv >> 3, kv = bkv & 7;
  int tid = threadIdx.x;
  int wave = tid >> 6, lane = tid & 63;
  int row0 = b * 32 + kv * 4;
  float kth0 = kthM[(row0 + 0) * 2], M0 = kthM[(row0 + 0) * 2 + 1];
  float kth1 = kthM[(row0 + 1) * 2], M1 = kthM[(row0 + 1) * 2 + 1];
  float kth2 = kthM[(row0 + 2) * 2], M2 = kthM[(row0 + 2) * 2 + 1];
  float kth3 = kthM[(row0 + 3) * 2], M3 = kthM[(row0 + 3) * 2 + 1];
  const float* s0r = scores + (size_t)(row0 + 0) * LP_;
  const float* s1r = scores + (size_t)(row0 + 1) * LP_;
  const float* s2r = scores + (size_t)(row0 + 2) * LP_;
  const float* s3r = scores + (size_t)(row0 + 3) * LP_;
  const float* vbase = vcache + ((size_t)(b * NKV_ + kv) * S_) * D_;
  const float* vnrow = vnew + (size_t)(b * NKV_ + kv) * D_;

  __shared__ int   s_idx[256];
  __shared__ float s_w[4][256];
  __shared__ int   s_cnt[4];
  __shared__ float s_acc[4][4][128];
  __shared__ float s_z[4][4];

  // ---- phase 1: scan 4 head rows, per-wave ballot-compact ----
  {
    int p = chunk * CHUNK_ + wave * 64 + lane;
    bool valid = (p < L_);
    float v0 = 0.f, v1 = 0.f, v2 = 0.f, v3 = 0.f;
    bool k0 = false, k1 = false, k2 = false, k3 = false;
    if (valid) {
      v0 = s0r[p]; v1 = s1r[p]; v2 = s2r[p]; v3 = s3r[p];
      bool always = (p < INIT_) || (p >= L_ - LOCAL_);
      k0 = always || (v0 >= kth0);
      k1 = always || (v1 >= kth1);
      k2 = always || (v2 >= kth2);
      k3 = always || (v3 >= kth3);
    }
    bool any = k0 | k1 | k2 | k3;
    unsigned long long mask = __ballot(any);
    if (any) {
      int rank = __popcll(mask & ((1ull << lane) - 1ull));
      int slot = wave * 64 + rank;
      s_idx[slot] = p;
      s_w[0][slot] = k0 ? __expf(v0 - M0) : 0.0f;
      s_w[1][slot] = k1 ? __expf(v1 - M1) : 0.0f;
      s_w[2][slot] = k2 ? __expf(v2 - M2) : 0.0f;
      s_w[3][slot] = k3 ? __expf(v3 - M3) : 0.0f;
    }
    if (lane == 0) s_cnt[wave] = __popcll(mask);
  }
  __syncthreads();

  // ---- phase 1b: left-compact the 4 wave segments into one contiguous list ----
  int cnt0 = s_cnt[0], cnt1 = s_cnt[1], cnt2 = s_cnt[2], cnt3 = s_cnt[3];
  int off[4] = {0, cnt0, cnt0 + cnt1, cnt0 + cnt1 + cnt2};
  int total = off[3] + cnt3;
  {
    int w = tid >> 6, r = tid & 63;
    bool has = r < s_cnt[w];
    int vi = 0; float w0v = 0, w1v = 0, w2v = 0, w3v = 0;
    if (has) {
      vi = s_idx[tid];
      w0v = s_w[0][tid]; w1v = s_w[1][tid]; w2v = s_w[2][tid]; w3v = s_w[3][tid];
    }
    __syncthreads();
    if (has) {
      int np = off[w] + r;
      s_idx[np] = vi;
      s_w[0][np] = w0v; s_w[1][np] = w1v; s_w[2][np] = w2v; s_w[3][np] = w3v;
    }
  }
  __syncthreads();

  // ---- phase 2: gather V rows; half-wave per row; dequant once, 4 accumulators ----
  int hw = tid >> 5, sub = tid & 31;
  int par = sub & 1;
  float4 a0 = make_float4(0.f, 0.f, 0.f, 0.f);
  float4 a1 = a0, a2 = a0, a3 = a0;
  float z0 = 0.f, z1 = 0.f, z2 = 0.f, z3 = 0.f;
  #pragma unroll 2
  for (int j = hw; j < total; j += 8) {
    int l = s_idx[j];
    float4 v = (l < S_) ? ntload4(vbase + (size_t)l * D_ + sub * 4)
                        : *(const float4*)(vnrow + sub * 4);
    float mn0 = fminf(fminf(v.x, v.y), fminf(v.z, v.w));
    float mx0 = fmaxf(fmaxf(v.x, v.y), fmaxf(v.z, v.w));
    float mn, mx;
    minmax32(par, mn0, mx0, mn, mx);
    float rng = mx - mn; rng = (rng == 0.0f) ? 1.0f : rng;
    float scale = 15.0f / rng;
    float s2 = rng * (1.0f / 15.0f);
    float vx = fmaf(fminf(fmaxf(rintf((v.x - mn) * scale), 0.0f), 15.0f), s2, mn);
    float vy = fmaf(fminf(fmaxf(rintf((v.y - mn) * scale), 0.0f), 15.0f), s2, mn);
    float vz = fmaf(fminf(fmaxf(rintf((v.z - mn) * scale), 0.0f), 15.0f), s2, mn);
    float vw = fmaf(fminf(fmaxf(rintf((v.w - mn) * scale), 0.0f), 15.0f), s2, mn);
    float w0 = s_w[0][j], w1 = s_w[1][j];
    float w2 = s_w[2][j], w3 = s_w[3][j];
    a0.x = fmaf(w0, vx, a0.x); a0.y = fmaf(w0, vy, a0.y);
    a0.z = fmaf(w0, vz, a0.z); a0.w = fmaf(w0, vw, a0.w); z0 += w0;
    a1.x = fmaf(w1, vx, a1.x); a1.y = fmaf(w1, vy, a1.y);
    a1.z = fmaf(w1, vz, a1.z); a1.w = fmaf(w1, vw, a1.w); z1 += w1;
    a2.x = fmaf(w2, vx, a2.x); a2.y = fmaf(w2, vy, a2.y);
    a2.z = fmaf(w2, vz, a2.z); a2.w = fmaf(w2, vw, a2.w); z2 += w2;
    a3.x = fmaf(w3, vx, a3.x); a3.y = fmaf(w3, vy, a3.y);
    a3.z = fmaf(w3, vz, a3.z); a3.w = fmaf(w3, vw, a3.w); z3 += w3;
  }
  // combine half-wave pairs in-register (lane i += lane i^32), halving LDS staging
  a0.x += __shfl_xor(a0.x, 32); a0.y += __shfl_xor(a0.y, 32);
  a0.z += __shfl_xor(a0.z, 32); a0.w += __shfl_xor(a0.w, 32);
  a1.x += __shfl_xor(a1.x, 32); a1.y += __shfl_xor(a1.y, 32);
  a1.z += __shfl_xor(a1.z, 32); a1.w += __shfl_xor(a1.w, 32);
  a2.x += __shfl_xor(a2.x, 32); a2.y += __shfl_xor(a2.y, 32);
  a2.z += __shfl_xor(a2.z, 32); a2.w += __shfl_xor(a2.w, 32);
  a3.x += __shfl_xor(a3.x, 32); a3.y += __shfl_xor(a3.y, 32);
  a3.z += __shfl_xor(a3.z, 32); a3.w += __shfl_xor(a3.w, 32);
  z0 += __shfl_xor(z0, 32); z1 += __shfl_xor(z1, 32);
  z2 += __shfl_xor(z2, 32); z3 += __shfl_xor(z3, 32);
  if (lane < 32) {
    *(float4*)(&s_acc[wave][0][sub * 4]) = a0;
    *(float4*)(&s_acc[wave][1][sub * 4]) = a1;
    *(float4*)(&s_acc[wave][2][sub * 4]) = a2;
    *(float4*)(&s_acc[wave][3][sub * 4]) = a3;
    if (sub == 0) {
      s_z[wave][0] = z0; s_z[wave][1] = z1; s_z[wave][2] = z2; s_z[wave][3] = z3;
    }
  }
  __syncthreads();

  // partials[bkv][chunk][g][129]
  float* pbase = partials + ((size_t)(bkv * NCHUNK_ + chunk) * 4) * 129;
  #pragma unroll
  for (int base2 = 0; base2 < 512; base2 += 256) {
    int id = base2 + tid;
    int g = id >> 7, d = id & 127;
    float a = 0.f;
    #pragma unroll
    for (int k = 0; k < 4; ++k) a += s_acc[k][g][d];
    pbase[g * 129 + d] = a;
  }
  if (tid < 4) {
    float zz = 0.f;
    #pragma unroll
    for (int k = 0; k < 4; ++k) zz += s_z[k][tid];
    pbase[tid * 129 + 128] = zz;
  }
}

// ---------------- Kernel E3: deterministic chunk reduce + normalize -------------------
__global__ __launch_bounds__(128) void k_fin(const float* __restrict__ partials,
    float* __restrict__ attn) {
  int row = blockIdx.x, d = threadIdx.x;
  int b = row >> 5, h = row & 31, kv = h >> 2, g = h & 3;
  int bkv = b * 8 + kv;
  float a = 0.f, z = 0.f;
  for (int c = 0; c < NCHUNK_; ++c) {
    const float* p = partials + ((size_t)(bkv * NCHUNK_ + c) * 4 + g) * 129;
    a += p[d];
    z += p[128];
  }
  attn[(size_t)row * 128 + d] = a / z;
}

// ---------------- Kernel F: output projection -----------------------------------------
__global__ __launch_bounds__(256) void k_out(const float* __restrict__ attn,
    const float* __restrict__ Wo, float* __restrict__ out) {
  int gw = (blockIdx.x * 256 + threadIdx.x) >> 6;   // 0..4095
  int lane = threadIdx.x & 63;
  const float* W = Wo + (size_t)gw * H_;
  float a0 = 0.f, a1 = 0.f, a2 = 0.f, a3 = 0.f;
  #pragma unroll 4
  for (int it = 0; it < 16; ++it) {
    int i = it * 256 + lane * 4;
    float4 w4 = ntload4(W + i);   // stream-once Wo
    float4 x0 = *(const float4*)(attn + 0 * H_ + i);
    float4 x1 = *(const float4*)(attn + 1 * H_ + i);
    float4 x2 = *(const float4*)(attn + 2 * H_ + i);
    float4 x3 = *(const float4*)(attn + 3 * H_ + i);
    a0 += w4.x * x0.x + w4.y * x0.y + w4.z * x0.z + w4.w * x0.w;
    a1 += w4.x * x1.x + w4.y * x1.y + w4.z * x1.z + w4.w * x1.w;
    a2 += w4.x * x2.x + w4.y * x2.y + w4.z * x2.z + w4.w * x2.w;
    a3 += w4.x * x3.x + w4.y * x3.y + w4.z * x3.z + w4.w * x3.w;
  }
  float pa = (lane & 1) ? a1 : a0, xa = (lane & 1) ? a0 : a1;
  pa += __shfl_xor(xa, 1);
  float pb = (lane & 1) ? a3 : a2, xb = (lane & 1) ? a2 : a3;
  pb += __shfl_xor(xb, 1);
  float c = (lane & 2) ? pb : pa, xc = (lane & 2) ? pa : pb;
  c += __shfl_xor(xc, 2);
  c += __shfl_xor(c, 4);
  c += __shfl_xor(c, 8);
  c += __shfl_xor(c, 16);
  c += __shfl_xor(c, 32);
  if (lane < 4) out[(size_t)lane * H_ + gw] = c;
}

extern "C" void kernel_launch(void* const* d_in, const int* in_sizes, int n_in,
                              void* d_out, int out_size, void* d_ws, size_t ws_size,
                              hipStream_t stream) {
  const float* hs     = (const float*)d_in[0];
  const float* kcache = (const float*)d_in[1];
  const float* vcache = (const float*)d_in[2];
  const float* cosv   = (const float*)d_in[3];
  const float* sinv   = (const float*)d_in[4];
  const float* Wq     = (const float*)d_in[5];
  const float* Wk     = (const float*)d_in[6];
  const float* Wv     = (const float*)d_in[7];
  const float* Wo     = (const float*)d_in[8];
  float* out = (float*)d_out;

  float* ws = (float*)d_ws;
  float* qraw     = ws;                      // 16384
  float* kraw     = qraw + 16384;            // 4096
  float* vnew     = kraw + 4096;             // 4096
  float* scores   = vnew + 4096;             // 128 rows x LP_ = 2097664
  float* kthM     = scores + 2097664;        // 256
  float* partials = kthM + 256;              // 32*65*4*129 = 1073280
  float* attn     = partials + 1073280;      // 16384
  (void)in_sizes; (void)n_in; (void)out_size; (void)ws_size;

  hipLaunchKernelGGL(k_proj,   dim3(1536),        dim3(256),  0, stream, hs, Wq, Wk, Wv, qraw, kraw, vnew);
  hipLaunchKernelGGL(k_scores, dim3(128, 32),     dim3(256),  0, stream, kcache, kraw, qraw, cosv, sinv, scores);
  hipLaunchKernelGGL(k_topk,   dim3(128),         dim3(1024), 0, stream, scores, kthM);
  hipLaunchKernelGGL(k_pv,     dim3(NCHUNK_, 32), dim3(256),  0, stream, scores, kthM, vcache, vnew, partials);
  hipLaunchKernelGGL(k_fin,    dim3(128),         dim3(128),  0, stream, partials, attn);
  hipLaunchKernelGGL(k_out,    dim3(1024),        dim3(256),  0, stream, attn, Wo, out);
}

// Round 15
// 150.860 us; speedup vs baseline: 1.0296x; 1.0296x over previous
//
#include <hip/hip_runtime.h>
#include <hip/hip_bf16.h>
#include <float.h>

#define B_ 4
#define NH_ 32
#define NKV_ 8
#define D_ 128
#define S_ 16384
#define L_ 16385
#define LP_ 16388   // padded score-row stride (16B-aligned rows)
#define H_ 4096
#define INIT_ 128
#define LOCAL_ 128
#define HEAVY_ 2048
#define CHUNK_ 256
#define NCHUNK_ 65   // 64*256 = 16384, chunk 64 holds only l = 16384

typedef float vf4 __attribute__((ext_vector_type(4)));

__device__ __forceinline__ unsigned f2key(float f) {
  unsigned u = __float_as_uint(f);
  return (u & 0x80000000u) ? ~u : (u | 0x80000000u);
}
__device__ __forceinline__ float key2f(unsigned k) {
  unsigned u = (k & 0x80000000u) ? (k & 0x7FFFFFFFu) : ~k;
  return __uint_as_float(u);
}

__device__ __forceinline__ float4 ntload4(const float* p) {
  vf4 v = __builtin_nontemporal_load((const vf4*)p);
  return make_float4(v.x, v.y, v.z, v.w);
}

// packed min/max reduce over 32 lanes (6 shfl instead of 10).
__device__ __forceinline__ void minmax32(int par, float mn0, float mx0, float& mn, float& mx) {
  float v = par ? -mx0 : mn0;
  float x = par ? mn0 : -mx0;
  v = fminf(v, __shfl_xor(x, 1));
  v = fminf(v, __shfl_xor(v, 2));
  v = fminf(v, __shfl_xor(v, 4));
  v = fminf(v, __shfl_xor(v, 8));
  v = fminf(v, __shfl_xor(v, 16));
  float t = __shfl_xor(v, 1);
  mn = par ? t : v;
  mx = -(par ? v : t);
}

// quantize K row fragment + 4 GQA dots + pair-merged reduce + store (lanes sub<4)
__device__ __forceinline__ void quant_dot_store(float4 kx,
    const float4& q0, const float4& q1, const float4& q2, const float4& q3,
    int sub, int par, float* __restrict__ srowbase, int l) {
  float mn0 = fminf(fminf(kx.x, kx.y), fminf(kx.z, kx.w));
  float mx0 = fmaxf(fmaxf(kx.x, kx.y), fmaxf(kx.z, kx.w));
  float mn, mx;
  minmax32(par, mn0, mx0, mn, mx);
  float rng = mx - mn; rng = (rng == 0.0f) ? 1.0f : rng;
  float scale = 15.0f / rng;          // IEEE divide: match reference rint boundaries
  float s2 = rng * (1.0f / 15.0f);
  float dx = fmaf(fminf(fmaxf(rintf((kx.x - mn) * scale), 0.0f), 15.0f), s2, mn);
  float dy = fmaf(fminf(fmaxf(rintf((kx.y - mn) * scale), 0.0f), 15.0f), s2, mn);
  float dz = fmaf(fminf(fmaxf(rintf((kx.z - mn) * scale), 0.0f), 15.0f), s2, mn);
  float dw = fmaf(fminf(fmaxf(rintf((kx.w - mn) * scale), 0.0f), 15.0f), s2, mn);
  float d0 = dx * q0.x + dy * q0.y + dz * q0.z + dw * q0.w;
  float d1 = dx * q1.x + dy * q1.y + dz * q1.z + dw * q1.w;
  float d2 = dx * q2.x + dy * q2.y + dz * q2.z + dw * q2.w;
  float d3 = dx * q3.x + dy * q3.y + dz * q3.z + dw * q3.w;
  // pair-merged 4-dot butterfly: 6 shfl
  float pa = par ? d1 : d0, xa = par ? d0 : d1;
  pa += __shfl_xor(xa, 1);
  float pb = par ? d3 : d2, xb = par ? d2 : d3;
  pb += __shfl_xor(xb, 1);
  float c = (sub & 2) ? pb : pa, xc = (sub & 2) ? pa : pb;
  c += __shfl_xor(xc, 2);
  c += __shfl_xor(c, 4);
  c += __shfl_xor(c, 8);
  c += __shfl_xor(c, 16);
  if (sub < 4) srowbase[(size_t)sub * LP_ + l] = c * 0.08838834764831845f;
}

// ---------------- Kernel A: q/k/v projections (one wave per output row, 4 batches) ----
__global__ __launch_bounds__(256) void k_proj(const float* __restrict__ hs,
    const float* __restrict__ Wq, const float* __restrict__ Wk, const float* __restrict__ Wv,
    float* __restrict__ qraw, float* __restrict__ kraw, float* __restrict__ vnew) {
  int gw = (blockIdx.x * 256 + threadIdx.x) >> 6;   // 0..6143
  int lane = threadIdx.x & 63;
  const float* W;
  if (gw < 4096)      W = Wq + (size_t)gw * H_;
  else if (gw < 5120) W = Wk + (size_t)(gw - 4096) * H_;
  else                W = Wv + (size_t)(gw - 5120) * H_;
  float a0 = 0.f, a1 = 0.f, a2 = 0.f, a3 = 0.f;
  #pragma unroll 4
  for (int it = 0; it < 16; ++it) {
    int h = it * 256 + lane * 4;
    float4 w4 = ntload4(W + h);   // stream-once: keep out of L2/L3
    float4 x0 = *(const float4*)(hs + 0 * H_ + h);
    float4 x1 = *(const float4*)(hs + 1 * H_ + h);
    float4 x2 = *(const float4*)(hs + 2 * H_ + h);
    float4 x3 = *(const float4*)(hs + 3 * H_ + h);
    a0 += w4.x * x0.x + w4.y * x0.y + w4.z * x0.z + w4.w * x0.w;
    a1 += w4.x * x1.x + w4.y * x1.y + w4.z * x1.z + w4.w * x1.w;
    a2 += w4.x * x2.x + w4.y * x2.y + w4.z * x2.z + w4.w * x2.w;
    a3 += w4.x * x3.x + w4.y * x3.y + w4.z * x3.z + w4.w * x3.w;
  }
  float pa = (lane & 1) ? a1 : a0, xa = (lane & 1) ? a0 : a1;
  pa += __shfl_xor(xa, 1);
  float pb = (lane & 1) ? a3 : a2, xb = (lane & 1) ? a2 : a3;
  pb += __shfl_xor(xb, 1);
  float c = (lane & 2) ? pb : pa, xc = (lane & 2) ? pa : pb;
  c += __shfl_xor(xc, 2);
  c += __shfl_xor(c, 4);
  c += __shfl_xor(c, 8);
  c += __shfl_xor(c, 16);
  c += __shfl_xor(c, 32);
  if (lane < 4) {   // lane r holds sum of batch r
    if (gw < 4096)      qraw[(size_t)lane * H_ + gw] = c;
    else if (gw < 5120) kraw[(size_t)lane * 1024 + (gw - 4096)] = c;
    else                vnew[(size_t)lane * 1024 + (gw - 5120)] = c;
  }
}

// ---------------- Kernel C: fused RoPE + scores with 4-bit pseudo-quantized K ---------
// grid (128, 32): 128 K rows per block; 8-deep load batching for MLP.
__global__ __launch_bounds__(256) void k_scores(const float* __restrict__ kcache,
    const float* __restrict__ kraw, const float* __restrict__ qraw,
    const float* __restrict__ cosv, const float* __restrict__ sinv,
    float* __restrict__ scores) {
  int wave = threadIdx.x >> 6, lane = threadIdx.x & 63;
  int half = lane >> 5, sub = lane & 31;
  int par = sub & 1;
  int bkv = blockIdx.y; int b = bkv >> 3, kv = bkv & 7;
  __shared__ __align__(16) float qsh[512];
  const float* qbase = qraw + (size_t)b * H_ + kv * 512;
  for (int i = threadIdx.x; i < 512; i += 256) {
    int d = i & 127;
    int j = (i & ~127) | ((d + 64) & 127);
    float x = qbase[i];
    float y = qbase[j];
    float p = (d < 64) ? -y : y;
    qsh[i] = x * cosv[d] + p * sinv[d];
  }
  __syncthreads();
  float4 q0 = *(const float4*)(qsh + 0 * 128 + sub * 4);
  float4 q1 = *(const float4*)(qsh + 1 * 128 + sub * 4);
  float4 q2 = *(const float4*)(qsh + 2 * 128 + sub * 4);
  float4 q3 = *(const float4*)(qsh + 3 * 128 + sub * 4);
  const float* kbase = kcache + ((size_t)(b * NKV_ + kv) * S_) * D_;
  float* srowbase = scores + (size_t)(b * NH_ + kv * 4) * LP_;

  int base = blockIdx.x * 128 + wave * 2 + half;
  for (int it8 = 0; it8 < 2; ++it8) {
    float4 kxs[8];
    #pragma unroll
    for (int u = 0; u < 8; ++u) {
      int l = base + (it8 * 8 + u) * 8;
      kxs[u] = ntload4(kbase + (size_t)l * D_ + sub * 4);   // stream-once K
    }
    #pragma unroll
    for (int u = 0; u < 8; ++u) {
      int l = base + (it8 * 8 + u) * 8;
      quant_dot_store(kxs[u], q0, q1, q2, q3, sub, par, srowbase, l);
    }
  }
  // tail: new RoPE'd k row at l = 16384, handled by block 127 half-wave 0
  if (blockIdx.x == 127 && wave == 0 && half == 0) {
    const float* kb = kraw + (size_t)b * 1024 + kv * 128;
    float el[4];
    #pragma unroll
    for (int e = 0; e < 4; ++e) {
      int d = sub * 4 + e;
      float x = kb[d];
      float y = kb[(d + 64) & 127];
      float p = (d < 64) ? -y : y;
      el[e] = x * cosv[d] + p * sinv[d];
    }
    float4 kx = make_float4(el[0], el[1], el[2], el[3]);
    quant_dot_store(kx, q0, q1, q2, q3, sub, par, srowbase, S_);
  }
}

// ---------------- Kernel D: exact 2048th-largest, register-resident radix select ------
// 1024 threads; 16 keys/thread (contiguous float4 loads). Wave-parallel suffix scans.
__global__ __launch_bounds__(1024) void k_topk(const float* __restrict__ scores,
    float* __restrict__ kthM) {
  int row = blockIdx.x;                 // b*32+h
  const float* srow = scores + (size_t)row * LP_;
  __shared__ unsigned binsP[4][4096];   // pass-1 privatized; binsP[0] reused later
  __shared__ unsigned chs[256];
  __shared__ float wmax[16];
  __shared__ unsigned s_cc, s_rem, s_d, s_k;
  int tid = threadIdx.x;
  int wid = tid >> 6, lane = tid & 63;
  unsigned* mybins = binsP[wid >> 2];

  // ---- load 16 contiguous values (4x float4); fold row max (incl. l=16384) ----
  unsigned keys[16];
  float lm = srow[16384];               // always-region: in max, never in histograms
  const float4* s4 = (const float4*)(srow + tid * 16);
  #pragma unroll
  for (int q = 0; q < 4; ++q) {
    float4 v = s4[q];
    lm = fmaxf(lm, fmaxf(fmaxf(v.x, v.y), fmaxf(v.z, v.w)));
    keys[q * 4 + 0] = f2key(v.x);
    keys[q * 4 + 1] = f2key(v.y);
    keys[q * 4 + 2] = f2key(v.z);
    keys[q * 4 + 3] = f2key(v.w);
  }
  #pragma unroll
  for (int m = 1; m < 64; m <<= 1) lm = fmaxf(lm, __shfl_xor(lm, m));
  if (lane == 0) wmax[wid] = lm;

  // ---- pass 1: top 12 bits, 4-way privatized ----
  for (int i = tid; i < 16384; i += 1024) ((unsigned*)binsP)[i] = 0;
  __syncthreads();
  #pragma unroll
  for (int j = 0; j < 16; ++j) {
    int l = tid * 16 + j;
    if (l >= 128 && l < 16257) atomicAdd(&mybins[keys[j] >> 20], 1u);
  }
  __syncthreads();
  if (tid < 256) {
    unsigned c = 0;
    #pragma unroll
    for (int j = 0; j < 16; ++j) {
      int bin = tid * 16 + j;
      c += binsP[0][bin] + binsP[1][bin] + binsP[2][bin] + binsP[3][bin];
    }
    chs[tid] = c;
  }
  __syncthreads();
  // coarse select over chs[256]: 4 bins/lane, wave-parallel suffix scan
  if (wid == 0) {
    unsigned c0 = chs[lane * 4], c1 = chs[lane * 4 + 1];
    unsigned c2 = chs[lane * 4 + 2], c3 = chs[lane * 4 + 3];
    unsigned s4v = c0 + c1 + c2 + c3;
    unsigned suf = s4v;
    #pragma unroll
    for (int off = 1; off < 64; off <<= 1) {
      unsigned t = __shfl_down(suf, off);
      suf += (lane + off < 64) ? t : 0u;
    }
    unsigned sufEx = suf - s4v;
    unsigned S3 = sufEx + c3, S2 = S3 + c2, S1 = S2 + c1, S0 = suf;
    unsigned K = HEAVY_;
    if (S0 >= K && S1 < K) { s_cc = lane * 4 + 0; s_rem = K - S1; }
    if (S1 >= K && S2 < K) { s_cc = lane * 4 + 1; s_rem = K - S2; }
    if (S2 >= K && S3 < K) { s_cc = lane * 4 + 2; s_rem = K - S3; }
    if (S3 >= K && sufEx < K) { s_cc = lane * 4 + 3; s_rem = K - sufEx; }
  }
  __syncthreads();
  // fine select (16 bins within coarse), 4-copy sums
  if (wid == 0 && lane < 16) {
    unsigned cc = s_cc, remc = s_rem;
    int bin = cc * 16 + lane;
    unsigned bv = binsP[0][bin] + binsP[1][bin] + binsP[2][bin] + binsP[3][bin];
    unsigned suf = bv;
    #pragma unroll
    for (int off = 1; off < 16; off <<= 1) {
      unsigned t = __shfl_down(suf, off);
      suf += (lane + off < 16) ? t : 0u;
    }
    unsigned sufEx = suf - bv;
    if (suf >= remc && sufEx < remc) { s_d = (unsigned)bin; s_k = remc - sufEx; }
  }
  __syncthreads();
  unsigned d1 = s_d, K2 = s_k;
  __syncthreads();

  // ---- pass 2: bits 19:8 within d1 ----
  for (int i = tid; i < 4096; i += 1024) binsP[0][i] = 0;
  __syncthreads();
  #pragma unroll
  for (int j = 0; j < 16; ++j) {
    int l = tid * 16 + j;
    if (l >= 128 && l < 16257) {
      unsigned u = keys[j];
      if ((u >> 20) == d1) atomicAdd(&binsP[0][(u >> 8) & 0xFFFu], 1u);
    }
  }
  __syncthreads();
  if (tid < 256) {
    unsigned c = 0;
    #pragma unroll
    for (int j = 0; j < 16; ++j) c += binsP[0][tid * 16 + j];
    chs[tid] = c;
  }
  __syncthreads();
  if (wid == 0) {
    unsigned c0 = chs[lane * 4], c1 = chs[lane * 4 + 1];
    unsigned c2 = chs[lane * 4 + 2], c3 = chs[lane * 4 + 3];
    unsigned s4v = c0 + c1 + c2 + c3;
    unsigned suf = s4v;
    #pragma unroll
    for (int off = 1; off < 64; off <<= 1) {
      unsigned t = __shfl_down(suf, off);
      suf += (lane + off < 64) ? t : 0u;
    }
    unsigned sufEx = suf - s4v;
    unsigned S3 = sufEx + c3, S2 = S3 + c2, S1 = S2 + c1, S0 = suf;
    unsigned K = K2;
    if (S0 >= K && S1 < K) { s_cc = lane * 4 + 0; s_rem = K - S1; }
    if (S1 >= K && S2 < K) { s_cc = lane * 4 + 1; s_rem = K - S2; }
    if (S2 >= K && S3 < K) { s_cc = lane * 4 + 2; s_rem = K - S3; }
    if (S3 >= K && sufEx < K) { s_cc = lane * 4 + 3; s_rem = K - sufEx; }
  }
  __syncthreads();
  if (wid == 0 && lane < 16) {
    unsigned cc = s_cc, remc = s_rem;
    int bin = cc * 16 + lane;
    unsigned bv = binsP[0][bin];
    unsigned suf = bv;
    #pragma unroll
    for (int off = 1; off < 16; off <<= 1) {
      unsigned t = __shfl_down(suf, off);
      suf += (lane + off < 16) ? t : 0u;
    }
    unsigned sufEx = suf - bv;
    if (suf >= remc && sufEx < remc) { s_d = (unsigned)bin; s_k = remc - sufEx; }
  }
  __syncthreads();
  unsigned d2 = s_d, K3 = s_k;
  __syncthreads();

  // ---- pass 3: low 8 bits within (d1,d2) ----
  if (tid < 256) binsP[0][tid] = 0;
  __syncthreads();
  unsigned pref = (d1 << 12) | d2;
  #pragma unroll
  for (int j = 0; j < 16; ++j) {
    int l = tid * 16 + j;
    if (l >= 128 && l < 16257) {
      unsigned u = keys[j];
      if ((u >> 8) == pref) atomicAdd(&binsP[0][u & 0xFFu], 1u);
    }
  }
  __syncthreads();
  if (wid == 0) {
    unsigned c0 = binsP[0][lane * 4], c1 = binsP[0][lane * 4 + 1];
    unsigned c2 = binsP[0][lane * 4 + 2], c3 = binsP[0][lane * 4 + 3];
    unsigned s4v = c0 + c1 + c2 + c3;
    unsigned suf = s4v;
    #pragma unroll
    for (int off = 1; off < 64; off <<= 1) {
      unsigned t = __shfl_down(suf, off);
      suf += (lane + off < 64) ? t : 0u;
    }
    unsigned sufEx = suf - s4v;
    unsigned S3 = sufEx + c3, S2 = S3 + c2, S1 = S2 + c1, S0 = suf;
    unsigned K = K3;
    int bb = -1;
    if (S0 >= K && S1 < K) bb = lane * 4 + 0;
    if (S1 >= K && S2 < K) bb = lane * 4 + 1;
    if (S2 >= K && S3 < K) bb = lane * 4 + 2;
    if (S3 >= K && sufEx < K) bb = lane * 4 + 3;
    if (bb >= 0) {
      unsigned ku = (d1 << 20) | (d2 << 8) | (unsigned)bb;
      float m = wmax[0];
      #pragma unroll
      for (int k = 1; k < 16; ++k) m = fmaxf(m, wmax[k]);
      kthM[row * 2 + 0] = key2f(ku);
      kthM[row * 2 + 1] = m;
    }
  }
}

// ---------------- Kernel E: union keep-list over 4 GQA heads + shared V gather --------
// grid (NCHUNK_, 32). Slim LDS (~13KB); cached V gather (nt hurt: scattered reuse).
__global__ __launch_bounds__(256) void k_pv(const float* __restrict__ scores,
    const float* __restrict__ kthM, const float* __restrict__ vcache,
    const float* __restrict__ vnew, float* __restrict__ partials) {
  int chunk = blockIdx.x, bkv = blockIdx.y;
  int b = bkv >> 3, kv = bkv & 7;
  int tid = threadIdx.x;
  int wave = tid >> 6, lane = tid & 63;
  int row0 = b * 32 + kv * 4;
  float kth0 = kthM[(row0 + 0) * 2], M0 = kthM[(row0 + 0) * 2 + 1];
  float kth1 = kthM[(row0 + 1) * 2], M1 = kthM[(row0 + 1) * 2 + 1];
  float kth2 = kthM[(row0 + 2) * 2], M2 = kthM[(row0 + 2) * 2 + 1];
  float kth3 = kthM[(row0 + 3) * 2], M3 = kthM[(row0 + 3) * 2 + 1];
  const float* s0r = scores + (size_t)(row0 + 0) * LP_;
  const float* s1r = scores + (size_t)(row0 + 1) * LP_;
  const float* s2r = scores + (size_t)(row0 + 2) * LP_;
  const float* s3r = scores + (size_t)(row0 + 3) * LP_;
  const float* vbase = vcache + ((size_t)(b * NKV_ + kv) * S_) * D_;
  const float* vnrow = vnew + (size_t)(b * NKV_ + kv) * D_;

  __shared__ int   s_idx[256];
  __shared__ float s_w[4][256];
  __shared__ int   s_cnt[4];
  __shared__ float s_acc[4][4][128];
  __shared__ float s_z[4][4];

  // ---- phase 1: scan 4 head rows, per-wave ballot-compact ----
  {
    int p = chunk * CHUNK_ + wave * 64 + lane;
    bool valid = (p < L_);
    float v0 = 0.f, v1 = 0.f, v2 = 0.f, v3 = 0.f;
    bool k0 = false, k1 = false, k2 = false, k3 = false;
    if (valid) {
      v0 = s0r[p]; v1 = s1r[p]; v2 = s2r[p]; v3 = s3r[p];
      bool always = (p < INIT_) || (p >= L_ - LOCAL_);
      k0 = always || (v0 >= kth0);
      k1 = always || (v1 >= kth1);
      k2 = always || (v2 >= kth2);
      k3 = always || (v3 >= kth3);
    }
    bool any = k0 | k1 | k2 | k3;
    unsigned long long mask = __ballot(any);
    if (any) {
      int rank = __popcll(mask & ((1ull << lane) - 1ull));
      int slot = wave * 64 + rank;
      s_idx[slot] = p;
      s_w[0][slot] = k0 ? __expf(v0 - M0) : 0.0f;
      s_w[1][slot] = k1 ? __expf(v1 - M1) : 0.0f;
      s_w[2][slot] = k2 ? __expf(v2 - M2) : 0.0f;
      s_w[3][slot] = k3 ? __expf(v3 - M3) : 0.0f;
    }
    if (lane == 0) s_cnt[wave] = __popcll(mask);
  }
  __syncthreads();

  // ---- phase 1b: left-compact the 4 wave segments into one contiguous list ----
  int cnt0 = s_cnt[0], cnt1 = s_cnt[1], cnt2 = s_cnt[2], cnt3 = s_cnt[3];
  int off[4] = {0, cnt0, cnt0 + cnt1, cnt0 + cnt1 + cnt2};
  int total = off[3] + cnt3;
  {
    int w = tid >> 6, r = tid & 63;
    bool has = r < s_cnt[w];
    int vi = 0; float w0v = 0, w1v = 0, w2v = 0, w3v = 0;
    if (has) {
      vi = s_idx[tid];
      w0v = s_w[0][tid]; w1v = s_w[1][tid]; w2v = s_w[2][tid]; w3v = s_w[3][tid];
    }
    __syncthreads();
    if (has) {
      int np = off[w] + r;
      s_idx[np] = vi;
      s_w[0][np] = w0v; s_w[1][np] = w1v; s_w[2][np] = w2v; s_w[3][np] = w3v;
    }
  }
  __syncthreads();

  // ---- phase 2: gather V rows; half-wave per row; dequant once, 4 accumulators ----
  int hw = tid >> 5, sub = tid & 31;
  int par = sub & 1;
  float4 a0 = make_float4(0.f, 0.f, 0.f, 0.f);
  float4 a1 = a0, a2 = a0, a3 = a0;
  float z0 = 0.f, z1 = 0.f, z2 = 0.f, z3 = 0.f;
  #pragma unroll 2
  for (int j = hw; j < total; j += 8) {
    int l = s_idx[j];
    const float* vrow = (l < S_) ? (vbase + (size_t)l * D_) : vnrow;
    float4 v = *(const float4*)(vrow + sub * 4);
    float mn0 = fminf(fminf(v.x, v.y), fminf(v.z, v.w));
    float mx0 = fmaxf(fmaxf(v.x, v.y), fmaxf(v.z, v.w));
    float mn, mx;
    minmax32(par, mn0, mx0, mn, mx);
    float rng = mx - mn; rng = (rng == 0.0f) ? 1.0f : rng;
    float scale = 15.0f / rng;
    float s2 = rng * (1.0f / 15.0f);
    float vx = fmaf(fminf(fmaxf(rintf((v.x - mn) * scale), 0.0f), 15.0f), s2, mn);
    float vy = fmaf(fminf(fmaxf(rintf((v.y - mn) * scale), 0.0f), 15.0f), s2, mn);
    float vz = fmaf(fminf(fmaxf(rintf((v.z - mn) * scale), 0.0f), 15.0f), s2, mn);
    float vw = fmaf(fminf(fmaxf(rintf((v.w - mn) * scale), 0.0f), 15.0f), s2, mn);
    float w0 = s_w[0][j], w1 = s_w[1][j];
    float w2 = s_w[2][j], w3 = s_w[3][j];
    a0.x = fmaf(w0, vx, a0.x); a0.y = fmaf(w0, vy, a0.y);
    a0.z = fmaf(w0, vz, a0.z); a0.w = fmaf(w0, vw, a0.w); z0 += w0;
    a1.x = fmaf(w1, vx, a1.x); a1.y = fmaf(w1, vy, a1.y);
    a1.z = fmaf(w1, vz, a1.z); a1.w = fmaf(w1, vw, a1.w); z1 += w1;
    a2.x = fmaf(w2, vx, a2.x); a2.y = fmaf(w2, vy, a2.y);
    a2.z = fmaf(w2, vz, a2.z); a2.w = fmaf(w2, vw, a2.w); z2 += w2;
    a3.x = fmaf(w3, vx, a3.x); a3.y = fmaf(w3, vy, a3.y);
    a3.z = fmaf(w3, vz, a3.z); a3.w = fmaf(w3, vw, a3.w); z3 += w3;
  }
  // combine half-wave pairs in-register (lane i += lane i^32), halving LDS staging
  a0.x += __shfl_xor(a0.x, 32); a0.y += __shfl_xor(a0.y, 32);
  a0.z += __shfl_xor(a0.z, 32); a0.w += __shfl_xor(a0.w, 32);
  a1.x += __shfl_xor(a1.x, 32); a1.y += __shfl_xor(a1.y, 32);
  a1.z += __shfl_xor(a1.z, 32); a1.w += __shfl_xor(a1.w, 32);
  a2.x += __shfl_xor(a2.x, 32); a2.y += __shfl_xor(a2.y, 32);
  a2.z += __shfl_xor(a2.z, 32); a2.w += __shfl_xor(a2.w, 32);
  a3.x += __shfl_xor(a3.x, 32); a3.y += __shfl_xor(a3.y, 32);
  a3.z += __shfl_xor(a3.z, 32); a3.w += __shfl_xor(a3.w, 32);
  z0 += __shfl_xor(z0, 32); z1 += __shfl_xor(z1, 32);
  z2 += __shfl_xor(z2, 32); z3 += __shfl_xor(z3, 32);
  if (lane < 32) {
    *(float4*)(&s_acc[wave][0][sub * 4]) = a0;
    *(float4*)(&s_acc[wave][1][sub * 4]) = a1;
    *(float4*)(&s_acc[wave][2][sub * 4]) = a2;
    *(float4*)(&s_acc[wave][3][sub * 4]) = a3;
    if (sub == 0) {
      s_z[wave][0] = z0; s_z[wave][1] = z1; s_z[wave][2] = z2; s_z[wave][3] = z3;
    }
  }
  __syncthreads();

  // partials[bkv][chunk][g][129]
  float* pbase = partials + ((size_t)(bkv * NCHUNK_ + chunk) * 4) * 129;
  #pragma unroll
  for (int base2 = 0; base2 < 512; base2 += 256) {
    int id = base2 + tid;
    int g = id >> 7, d = id & 127;
    float a = 0.f;
    #pragma unroll
    for (int k = 0; k < 4; ++k) a += s_acc[k][g][d];
    pbase[g * 129 + d] = a;
  }
  if (tid < 4) {
    float zz = 0.f;
    #pragma unroll
    for (int k = 0; k < 4; ++k) zz += s_z[k][tid];
    pbase[tid * 129 + 128] = zz;
  }
}

// ---------------- Kernel E3: deterministic chunk reduce + normalize -------------------
__global__ __launch_bounds__(128) void k_fin(const float* __restrict__ partials,
    float* __restrict__ attn) {
  int row = blockIdx.x, d = threadIdx.x;
  int b = row >> 5, h = row & 31, kv = h >> 2, g = h & 3;
  int bkv = b * 8 + kv;
  float a = 0.f, z = 0.f;
  for (int c = 0; c < NCHUNK_; ++c) {
    const float* p = partials + ((size_t)(bkv * NCHUNK_ + c) * 4 + g) * 129;
    a += p[d];
    z += p[128];
  }
  attn[(size_t)row * 128 + d] = a / z;
}

// ---------------- Kernel F: output projection -----------------------------------------
__global__ __launch_bounds__(256) void k_out(const float* __restrict__ attn,
    const float* __restrict__ Wo, float* __restrict__ out) {
  int gw = (blockIdx.x * 256 + threadIdx.x) >> 6;   // 0..4095
  int lane = threadIdx.x & 63;
  const float* W = Wo + (size_t)gw * H_;
  float a0 = 0.f, a1 = 0.f, a2 = 0.f, a3 = 0.f;
  #pragma unroll 4
  for (int it = 0; it < 16; ++it) {
    int i = it * 256 + lane * 4;
    float4 w4 = ntload4(W + i);   // stream-once Wo
    float4 x0 = *(const float4*)(attn + 0 * H_ + i);
    float4 x1 = *(const float4*)(attn + 1 * H_ + i);
    float4 x2 = *(const float4*)(attn + 2 * H_ + i);
    float4 x3 = *(const float4*)(attn + 3 * H_ + i);
    a0 += w4.x * x0.x + w4.y * x0.y + w4.z * x0.z + w4.w * x0.w;
    a1 += w4.x * x1.x + w4.y * x1.y + w4.z * x1.z + w4.w * x1.w;
    a2 += w4.x * x2.x + w4.y * x2.y + w4.z * x2.z + w4.w * x2.w;
    a3 += w4.x * x3.x + w4.y * x3.y + w4.z * x3.z + w4.w * x3.w;
  }
  float pa = (lane & 1) ? a1 : a0, xa = (lane & 1) ? a0 : a1;
  pa += __shfl_xor(xa, 1);
  float pb = (lane & 1) ? a3 : a2, xb = (lane & 1) ? a2 : a3;
  pb += __shfl_xor(xb, 1);
  float c = (lane & 2) ? pb : pa, xc = (lane & 2) ? pa : pb;
  c += __shfl_xor(xc, 2);
  c += __shfl_xor(c, 4);
  c += __shfl_xor(c, 8);
  c += __shfl_xor(c, 16);
  c += __shfl_xor(c, 32);
  if (lane < 4) out[(size_t)lane * H_ + gw] = c;
}

extern "C" void kernel_launch(void* const* d_in, const int* in_sizes, int n_in,
                              void* d_out, int out_size, void* d_ws, size_t ws_size,
                              hipStream_t stream) {
  const float* hs     = (const float*)d_in[0];
  const float* kcache = (const float*)d_in[1];
  const float* vcache = (const float*)d_in[2];
  const float* cosv   = (const float*)d_in[3];
  const float* sinv   = (const float*)d_in[4];
  const float* Wq     = (const float*)d_in[5];
  const float* Wk     = (const float*)d_in[6];
  const float* Wv     = (const float*)d_in[7];
  const float* Wo     = (const float*)d_in[8];
  float* out = (float*)d_out;

  float* ws = (float*)d_ws;
  float* qraw     = ws;                      // 16384
  float* kraw     = qraw + 16384;            // 4096
  float* vnew     = kraw + 4096;             // 4096
  float* scores   = vnew + 4096;             // 128 rows x LP_ = 2097664
  float* kthM     = scores + 2097664;        // 256
  float* partials = kthM + 256;              // 32*65*4*129 = 1073280
  float* attn     = partials + 1073280;      // 16384
  (void)in_sizes; (void)n_in; (void)out_size; (void)ws_size;

  hipLaunchKernelGGL(k_proj,   dim3(1536),        dim3(256),  0, stream, hs, Wq, Wk, Wv, qraw, kraw, vnew);
  hipLaunchKernelGGL(k_scores, dim3(128, 32),     dim3(256),  0, stream, kcache, kraw, qraw, cosv, sinv, scores);
  hipLaunchKernelGGL(k_topk,   dim3(128),         dim3(1024), 0, stream, scores, kthM);
  hipLaunchKernelGGL(k_pv,     dim3(NCHUNK_, 32), dim3(256),  0, stream, scores, kthM, vcache, vnew, partials);
  hipLaunchKernelGGL(k_fin,    dim3(128),         dim3(128),  0, stream, partials, attn);
  hipLaunchKernelGGL(k_out,    dim3(1024),        dim3(256),  0, stream, attn, Wo, out);
}